// Round 6
// baseline (2673.025 us; speedup 1.0000x reference)
//
#include <hip/hip_runtime.h>
#include <hip/hip_bf16.h>

#define BB 512
#define SS 256
#define HH 256
#define DD 64
#define TT 50
#define GG 1024   // 4*H
#define INW 129

typedef _Float16 h4 __attribute__((ext_vector_type(4)));
typedef _Float16 h8 __attribute__((ext_vector_type(8)));
typedef __fp16 hf2 __attribute__((ext_vector_type(2)));   // builtin-facing f16 pair
typedef float f32x4 __attribute__((ext_vector_type(4)));
typedef unsigned int u32;

__device__ inline float sigf(float x) { return 1.f / (1.f + __expf(-x)); }
__device__ inline float tanhf_(float x) { return 1.f - 2.f / (__expf(2.f * x) + 1.f); }

__device__ inline u32 pkrtz(float a, float b) {
    hf2 h = __builtin_amdgcn_cvt_pkrtz(a, b);
    return __builtin_bit_cast(u32, h);
}

// ============ prep ============
// Bhh/Bih: unchanged validated round-5 layouts.
// A1f[(t*2+ks)*64+l] (h8)  = Wd1[16t+(l&15)][32ks+8(l>>4)+e]   (t<16, ks<2)
// A2f[(t2*8+ks)*64+l] (h8) = Wd2[16t2+(l&15)][32ks+8(l>>4)+e]  (t2<4, ks<8)
__global__ __launch_bounds__(256) void prep_kernel(
    const float* __restrict__ W_hh, const float* __restrict__ W_ih,
    const float* __restrict__ Wd1, const float* __restrict__ Wd2,
    h4* __restrict__ BhhV4, h4* __restrict__ BhhL4, h4* __restrict__ BhhS4,
    _Float16* __restrict__ Bih, h4* __restrict__ A1f4, h4* __restrict__ A2f4)
{
    int idx = blockIdx.x * 256 + threadIdx.x;
    if (idx < 65536) {
        int eh = idx & 1;
        int l = (idx >> 1) & 63;
        int ks = (idx >> 7) & 7;
        int s = (idx >> 10) & 7;
        int w = (idx >> 13) & 7;
        int g = s & 3, jt = s >> 2;
        int n = g * 256 + w * 32 + jt * 16 + (l & 15);
        int k = 32 * ks + 8 * (l >> 4) + 4 * eh;
        float4 v = *(const float4*)(W_hh + (size_t)n * HH + k);
        h4 o; o[0] = (_Float16)v.x; o[1] = (_Float16)v.y; o[2] = (_Float16)v.z; o[3] = (_Float16)v.w;
        if (ks < 4)      BhhV4[(((w * 8 + s) * 4 + ks) * 64 + l) * 2 + eh] = o;
        else if (ks < 6) BhhL4[(((w * 8 + s) * 2 + (ks - 4)) * 64 + l) * 2 + eh] = o;
        else             BhhS4[(((w * 8 + s) * 2 + (ks - 6)) * 64 + l) * 2 + eh] = o;
    } else if (idx < 106496) {
        int fj = idx - 65536;
        int eh = fj & 1;
        int l = (fj >> 1) & 63;
        int si = fj >> 7;              // [0,320) = ntile*5 + ks
        int ks = si % 5;
        int ntile = si / 5;
        int n = ntile * 16 + (l & 15);
        int k = 32 * ks + 8 * (l >> 4) + 4 * eh;
        h4 o;
#pragma unroll
        for (int i = 0; i < 4; i++) {
            int kk = k + i;
            o[i] = (_Float16)((kk < INW) ? W_ih[(size_t)n * INW + kk] : 0.f);
        }
        *(h4*)(Bih + (size_t)fj * 4) = o;
    } else if (idx < 110592) {
        int fj = idx - 106496;         // A1f: 32 slots * 64 lanes * 2
        int eh = fj & 1;
        int l = (fj >> 1) & 63;
        int slot = fj >> 7;            // t*2+ks
        int ks = slot & 1, t = slot >> 1;
        int row = 16 * t + (l & 15);
        int k = 32 * ks + 8 * (l >> 4) + 4 * eh;
        h4 o;
#pragma unroll
        for (int i = 0; i < 4; i++) o[i] = (_Float16)Wd1[(size_t)row * DD + k + i];
        A1f4[fj] = o;
    } else if (idx < 114688) {
        int fj = idx - 110592;         // A2f: 32 slots * 64 lanes * 2
        int eh = fj & 1;
        int l = (fj >> 1) & 63;
        int slot = fj >> 7;            // t2*8+ks
        int ks = slot & 7, t2 = slot >> 3;
        int row = 16 * t2 + (l & 15);
        int k = 32 * ks + 8 * (l >> 4) + 4 * eh;
        h4 o;
#pragma unroll
        for (int i = 0; i < 4; i++) o[i] = (_Float16)Wd2[(size_t)row * HH + k + i];
        A2f4[fj] = o;
    }
}

// ============ xw GEMM (MFMA): validated round-5 kernel, unchanged ============
__global__ __launch_bounds__(256) void xw_kernel(
    const float* __restrict__ x, const _Float16* __restrict__ Bih,
    const float* __restrict__ b_ih, const float* __restrict__ b_hh,
    h4* __restrict__ xwf)
{
    __shared__ __align__(16) _Float16 ash[4][5][64][8];   // 20 KB, A-frag layout
    int tid = threadIdx.x;
    int w4 = tid >> 6, l = tid & 63;
    int bx = blockIdx.x;
    int t = bx >> 3, Bb = bx & 7;           // 64 batch-rows: b = Bb*64 + rr

    for (int i = tid; i < 64 * 160; i += 256) {
        int rr = i / 160, kk = i % 160;
        float v = (kk < INW) ? x[((size_t)(Bb * 64 + rr) * SS + t) * INW + kk] : 0.f;
        ash[rr >> 4][kk >> 5][(((kk & 31) >> 3) << 4) + (rr & 15)][kk & 7] = (_Float16)v;
    }
    __syncthreads();

    h8 A[4][5];
#pragma unroll
    for (int ms = 0; ms < 4; ms++)
#pragma unroll
        for (int ks = 0; ks < 5; ks++)
            A[ms][ks] = *(h8*)&ash[ms][ks][l][0];

    const h8* Bih8 = (const h8*)Bih;
    for (int nt16 = 0; nt16 < 16; nt16++) {
        int ntile = w4 * 16 + nt16;
        h8 Bv[5];
#pragma unroll
        for (int ks = 0; ks < 5; ks++) Bv[ks] = Bih8[(ntile * 5 + ks) * 64 + l];
        int nb = ntile * 16 + (l & 15);
        float bias = b_ih[nb] + b_hh[nb];
        f32x4 acc[4];
#pragma unroll
        for (int ms = 0; ms < 4; ms++) acc[ms] = (f32x4){0.f, 0.f, 0.f, 0.f};
#pragma unroll
        for (int ks = 0; ks < 5; ks++)
#pragma unroll
            for (int ms = 0; ms < 4; ms++)
                acc[ms] = __builtin_amdgcn_mfma_f32_16x16x32_f16(A[ms][ks], Bv[ks], acc[ms], 0, 0, 0);
        int slot = ((ntile & 15) >> 1) * 8 + (ntile & 1) * 4 + (ntile >> 4);
#pragma unroll
        for (int ms = 0; ms < 4; ms++) {
            int bg = Bb * 4 + ms;
            h4 o;
#pragma unroll
            for (int r = 0; r < 4; r++) o[r] = (_Float16)(acc[ms][r] + bias);
            xwf[(((size_t)bg * SS + t) * 64 + slot) * 64 + l] = o;
        }
    }
}

// ============ LSTM v4: 32 blocks x 512 thr; xv prefetch + swizzled h + early streams ============
__global__ __launch_bounds__(512, 2) void lstm_kernel(
    const h8* __restrict__ BhhV, const h8* __restrict__ BhhL, const h8* __restrict__ BhhS,
    const h4* __restrict__ xwf, const int* __restrict__ lengths, float* __restrict__ pooled)
{
    __shared__ __align__(16) _Float16 Wlds[65536];     // 128 KB: ks4-5 weight fragments
    __shared__ __align__(16) _Float16 hst[2][4096];    // 16 KB: swizzled [b][j] h, double-buffered
    int tid = threadIdx.x;
    int w = tid >> 6, l = tid & 63;
    int q = l >> 4, b0 = l & 15;
    int bg = blockIdx.x;

    {   // copy ks4-5 weights into LDS (linear, 128 KB)
        const uint4* src = (const uint4*)BhhL;
        uint4* dst = (uint4*)Wlds;
#pragma unroll
        for (int i = 0; i < 16; i++) dst[i * 512 + tid] = src[i * 512 + tid];
    }

    h8 Wv[8][4];
#pragma unroll
    for (int s = 0; s < 8; s++)
#pragma unroll
        for (int ks = 0; ks < 4; ks++)
            Wv[s][ks] = BhhV[((w * 8 + s) * 4 + ks) * 64 + l];

    int len_[4];
    float c_[2][4], pa[2][4];
#pragma unroll
    for (int r = 0; r < 4; r++) {
        len_[r] = lengths[bg * 16 + 4 * q + r];
#pragma unroll
        for (int jt = 0; jt < 2; jt++) { c_[jt][r] = 0.f; pa[jt][r] = 0.f; }
    }

    {   // zero h buffers (h0 = 0): 16 KB = 1024 uint4
        uint4* hz = (uint4*)hst;
        hz[tid] = make_uint4(0, 0, 0, 0);
        hz[512 + tid] = make_uint4(0, 0, 0, 0);
    }
    __syncthreads();

    // preload xv for t=0
    h4 xc[8], xn[8];
    {
        const h4* p0 = xwf + (((size_t)bg * SS + 0) * 64 + w * 8) * 64 + l;
#pragma unroll
        for (int s = 0; s < 8; s++) xc[s] = p0[s * 64];
    }

    int cur = 0;
    for (int t = 0; t < SS; t++) {
        // prefetch xv for t+1 (full-step latency coverage; wrap harmlessly at t=255)
        int tn = (t + 1) & 255;
        const h4* pn = xwf + (((size_t)bg * SS + tn) * 64 + w * 8) * 64 + l;
#pragma unroll
        for (int s = 0; s < 8; s++) xn[s] = pn[s * 64];

        int zoff = 0;
        asm volatile("" : "+v"(zoff));      // block LICM on streamed weights
        const h8* bS = BhhS + zoff;
#pragma unroll
        for (int jt = 0; jt < 2; jt++) {
            // issue ALL streamed frags (ks6,ks7 x 4 gates) before the covered MFMAs
            h8 Ws[8];
#pragma unroll
            for (int g = 0; g < 4; g++) {
                Ws[g]     = bS[((w * 8 + jt * 4 + g) * 2 + 0) * 64 + l];
                Ws[4 + g] = bS[((w * 8 + jt * 4 + g) * 2 + 1) * 64 + l];
            }
            f32x4 acc[4];
#pragma unroll
            for (int g = 0; g < 4; g++) acc[g] = (f32x4){0.f, 0.f, 0.f, 0.f};
            // ks 0-3 from VGPR/AGPR weights
#pragma unroll
            for (int ks = 0; ks < 4; ks++) {
                h8 A = *(const h8*)&hst[cur][(b0 * 256 + 32 * ks + 8 * q) ^ ((b0 & 7) << 3)];
#pragma unroll
                for (int g = 0; g < 4; g++)
                    acc[g] = __builtin_amdgcn_mfma_f32_16x16x32_f16(A, Wv[jt * 4 + g][ks], acc[g], 0, 0, 0);
            }
            // ks 4-5 from LDS
#pragma unroll
            for (int ks = 4; ks < 6; ks++) {
                h8 A = *(const h8*)&hst[cur][(b0 * 256 + 32 * ks + 8 * q) ^ ((b0 & 7) << 3)];
#pragma unroll
                for (int g = 0; g < 4; g++) {
                    h8 Bw = *(const h8*)&Wlds[(((w * 8 + jt * 4 + g) * 2 + (ks - 4)) * 64 + l) * 8];
                    acc[g] = __builtin_amdgcn_mfma_f32_16x16x32_f16(A, Bw, acc[g], 0, 0, 0);
                }
            }
            // ks 6-7 from the streamed regs (loads landed during ks0-5)
            {
                h8 A = *(const h8*)&hst[cur][(b0 * 256 + 32 * 6 + 8 * q) ^ ((b0 & 7) << 3)];
#pragma unroll
                for (int g = 0; g < 4; g++)
                    acc[g] = __builtin_amdgcn_mfma_f32_16x16x32_f16(A, Ws[g], acc[g], 0, 0, 0);
            }
            {
                h8 A = *(const h8*)&hst[cur][(b0 * 256 + 32 * 7 + 8 * q) ^ ((b0 & 7) << 3)];
#pragma unroll
                for (int g = 0; g < 4; g++)
                    acc[g] = __builtin_amdgcn_mfma_f32_16x16x32_f16(A, Ws[4 + g], acc[g], 0, 0, 0);
            }
            // gates + h update
#pragma unroll
            for (int r = 0; r < 4; r++) {
                float gi = acc[0][r] + (float)xc[jt * 4 + 0][r];
                float gf = acc[1][r] + (float)xc[jt * 4 + 1][r];
                float gg = acc[2][r] + (float)xc[jt * 4 + 2][r];
                float go = acc[3][r] + (float)xc[jt * 4 + 3][r];
                float cc = sigf(gf) * c_[jt][r] + sigf(gi) * tanhf_(gg);
                c_[jt][r] = cc;
                float hh = sigf(go) * tanhf_(cc);
                if (t < len_[r]) pa[jt][r] += hh;
                int b = 4 * q + r;
                int j = w * 32 + jt * 16 + b0;
                hst[cur ^ 1][(b * 256 + j) ^ ((b & 7) << 3)] = (_Float16)hh;
            }
        }
        __syncthreads();
#pragma unroll
        for (int s = 0; s < 8; s++) xc[s] = xn[s];
        cur ^= 1;
    }

#pragma unroll
    for (int jt = 0; jt < 2; jt++)
#pragma unroll
        for (int r = 0; r < 4; r++) {
            int b = 4 * q + r;
            int j = w * 32 + jt * 16 + b0;
            pooled[(size_t)(bg * 16 + b) * HH + j] = pa[jt][r] / (float)len_[r];
        }
}

// ============ head: unchanged ============
__global__ __launch_bounds__(256) void head_kernel(
    const float* __restrict__ pooled, const float* __restrict__ Wp1,
    const float* __restrict__ bp1, const float* __restrict__ Wp2,
    const float* __restrict__ bp2, float* __restrict__ y0ws)
{
    __shared__ __align__(16) float psh[HH];
    __shared__ __align__(16) float rsh[HH];
    int tid = threadIdx.x, b = blockIdx.x;
    psh[tid] = pooled[(size_t)b * HH + tid];
    __syncthreads();
    float a = bp1[tid];
    const float* wr = Wp1 + (size_t)tid * HH;
#pragma unroll 8
    for (int k = 0; k < HH; k += 4) {
        float4 w = *(const float4*)(wr + k);
        a += psh[k] * w.x + psh[k + 1] * w.y + psh[k + 2] * w.z + psh[k + 3] * w.w;
    }
    rsh[tid] = fmaxf(a, 0.f);
    __syncthreads();
    if (tid < DD) {
        float acc = bp2[tid];
        const float* w2 = Wp2 + (size_t)tid * HH;
#pragma unroll 8
        for (int h = 0; h < HH; h += 4) {
            float4 w = *(const float4*)(w2 + h);
            acc += rsh[h] * w.x + rsh[h + 1] * w.y + rsh[h + 2] * w.z + rsh[h + 3] * w.w;
        }
        y0ws[(size_t)b * DD + tid] = acc;
    }
}

// ============ ODE v3: MFMA RK4, 16 batches/block, 4 waves, swapped operands ============
// State kept lane-local in B-frag layout: lane l owns batch bb=l&15, k in {8q..8q+7, 32+8q..+7}.
// GEMV1: C1 = mfma(W1-Afrag, y-Bfrag): col=batch, row=W1row. GEMV2: same with W2, h.
__global__ __launch_bounds__(256) void ode_kernel(
    const float* __restrict__ y0ws, const h8* __restrict__ A1f,
    const float* __restrict__ bd1, const h8* __restrict__ A2f,
    const float* __restrict__ bd2, const float* __restrict__ ltime,
    const float* __restrict__ lfeat, const float* __restrict__ lmask,
    float* __restrict__ pred, float* __restrict__ losso)
{
    __shared__ __align__(16) _Float16 hX[4096];   // swizzled [b][i], 8 KB
    __shared__ __align__(16) _Float16 kX[1024];   // swizzled [b][j], 2 KB
    int tid = threadIdx.x;
    int wv = tid >> 6, l = tid & 63;
    int q = l >> 4, bb = l & 15;
    int b = blockIdx.x * 16 + bb;

    // weights as A-fragments, resident in regs
    h8 A1[4][2];
#pragma unroll
    for (int tt = 0; tt < 4; tt++)
#pragma unroll
        for (int ks = 0; ks < 2; ks++)
            A1[tt][ks] = A1f[((4 * wv + tt) * 2 + ks) * 64 + l];
    h8 A2[8];
#pragma unroll
    for (int ks = 0; ks < 8; ks++) A2[ks] = A2f[(wv * 8 + ks) * 64 + l];

    float bd1c[4][4];
#pragma unroll
    for (int tt = 0; tt < 4; tt++)
#pragma unroll
        for (int r = 0; r < 4; r++) bd1c[tt][r] = bd1[16 * (4 * wv + tt) + 4 * q + r];
    float bd2c[4];
#pragma unroll
    for (int r = 0; r < 4; r++) bd2c[r] = bd2[16 * wv + 4 * q + r];

    float y[16], kp[16], ksum[16];
#pragma unroll
    for (int ks = 0; ks < 2; ks++)
#pragma unroll
        for (int e = 0; e < 8; e++) {
            y[ks * 8 + e] = y0ws[(size_t)b * DD + 32 * ks + 8 * q + e];
            kp[ks * 8 + e] = 0.f;
        }

    if (wv == 0) {   // pred/loss at ti=0
#pragma unroll
        for (int ks = 0; ks < 2; ks++) {
            size_t idx = ((size_t)b * TT + 0) * DD + 32 * ks + 8 * q;
            float4 p0 = make_float4(y[ks * 8 + 0], y[ks * 8 + 1], y[ks * 8 + 2], y[ks * 8 + 3]);
            float4 p1 = make_float4(y[ks * 8 + 4], y[ks * 8 + 5], y[ks * 8 + 6], y[ks * 8 + 7]);
            *(float4*)&pred[idx] = p0;
            *(float4*)&pred[idx + 4] = p1;
            float4 lf0 = *(const float4*)&lfeat[idx], lf1 = *(const float4*)&lfeat[idx + 4];
            float4 lm0 = *(const float4*)&lmask[idx], lm1 = *(const float4*)&lmask[idx + 4];
            float4 lo0, lo1;
            lo0.x = (p0.x - lf0.x) * (p0.x - lf0.x) * (1.f - lm0.x);
            lo0.y = (p0.y - lf0.y) * (p0.y - lf0.y) * (1.f - lm0.y);
            lo0.z = (p0.z - lf0.z) * (p0.z - lf0.z) * (1.f - lm0.z);
            lo0.w = (p0.w - lf0.w) * (p0.w - lf0.w) * (1.f - lm0.w);
            lo1.x = (p1.x - lf1.x) * (p1.x - lf1.x) * (1.f - lm1.x);
            lo1.y = (p1.y - lf1.y) * (p1.y - lf1.y) * (1.f - lm1.y);
            lo1.z = (p1.z - lf1.z) * (p1.z - lf1.z) * (1.f - lm1.z);
            lo1.w = (p1.w - lf1.w) * (p1.w - lf1.w) * (1.f - lm1.w);
            *(float4*)&losso[idx] = lo0;
            *(float4*)&losso[idx + 4] = lo1;
        }
    }

    for (int iv = 0; iv < TT - 1; iv++) {
        float t0 = ltime[(size_t)b * TT + iv], t1 = ltime[(size_t)b * TT + iv + 1];
        float dt = (t1 - t0) * 0.125f;
        for (int ss = 0; ss < 8; ss++) {
#pragma unroll
            for (int i = 0; i < 16; i++) ksum[i] = 0.f;
            const float AE[4] = {0.f, 0.5f, 0.5f, 1.f};
            const float WE[4] = {1.f, 2.f, 2.f, 1.f};
#pragma unroll
            for (int e = 0; e < 4; e++) {
                // build B1 (y-stage, f16 B-frag)
                h8 B1[2];
#pragma unroll
                for (int ks = 0; ks < 2; ks++) {
                    float ye[8];
#pragma unroll
                    for (int i = 0; i < 8; i++) ye[i] = y[ks * 8 + i] + AE[e] * dt * kp[ks * 8 + i];
                    uint4 u;
                    u.x = pkrtz(ye[0], ye[1]); u.y = pkrtz(ye[2], ye[3]);
                    u.z = pkrtz(ye[4], ye[5]); u.w = pkrtz(ye[6], ye[7]);
                    B1[ks] = __builtin_bit_cast(h8, u);
                }
                // GEMV1: 4 tiles x 2 ks
                f32x4 C1[4];
#pragma unroll
                for (int tt = 0; tt < 4; tt++) C1[tt] = (f32x4){0.f, 0.f, 0.f, 0.f};
#pragma unroll
                for (int ks = 0; ks < 2; ks++)
#pragma unroll
                    for (int tt = 0; tt < 4; tt++)
                        C1[tt] = __builtin_amdgcn_mfma_f32_16x16x32_f16(A1[tt][ks], B1[ks], C1[tt], 0, 0, 0);
                // relu + bias, pack, write hX
#pragma unroll
                for (int tt = 0; tt < 4; tt++) {
                    float h0 = fmaxf(C1[tt][0] + bd1c[tt][0], 0.f);
                    float h1 = fmaxf(C1[tt][1] + bd1c[tt][1], 0.f);
                    float h2 = fmaxf(C1[tt][2] + bd1c[tt][2], 0.f);
                    float h3 = fmaxf(C1[tt][3] + bd1c[tt][3], 0.f);
                    int i0 = 16 * (4 * wv + tt) + 4 * q;
                    int idx = (bb * 256 + i0) ^ ((bb & 7) << 3);
                    *(uint2*)&hX[idx] = make_uint2(pkrtz(h0, h1), pkrtz(h2, h3));
                }
                __syncthreads();
                // GEMV2: 1 tile x 8 ks, 2 chains
                f32x4 Ca = (f32x4){0.f, 0.f, 0.f, 0.f}, Cb = (f32x4){0.f, 0.f, 0.f, 0.f};
#pragma unroll
                for (int ks = 0; ks < 8; ks += 2) {
                    h8 B2a = *(const h8*)&hX[(bb * 256 + 32 * ks + 8 * q) ^ ((bb & 7) << 3)];
                    h8 B2b = *(const h8*)&hX[(bb * 256 + 32 * (ks + 1) + 8 * q) ^ ((bb & 7) << 3)];
                    Ca = __builtin_amdgcn_mfma_f32_16x16x32_f16(A2[ks], B2a, Ca, 0, 0, 0);
                    Cb = __builtin_amdgcn_mfma_f32_16x16x32_f16(A2[ks + 1], B2b, Cb, 0, 0, 0);
                }
                {
                    float k0 = Ca[0] + Cb[0] + bd2c[0];
                    float k1 = Ca[1] + Cb[1] + bd2c[1];
                    float k2 = Ca[2] + Cb[2] + bd2c[2];
                    float k3 = Ca[3] + Cb[3] + bd2c[3];
                    int j0 = 16 * wv + 4 * q;
                    int idx = (bb * 64 + j0) ^ ((bb & 7) << 3);
                    *(uint2*)&kX[idx] = make_uint2(pkrtz(k0, k1), pkrtz(k2, k3));
                }
                __syncthreads();
                // read kv back in B1 layout; update kp/ksum
#pragma unroll
                for (int ks = 0; ks < 2; ks++) {
                    h8 kvh = *(const h8*)&kX[(bb * 64 + 32 * ks + 8 * q) ^ ((bb & 7) << 3)];
#pragma unroll
                    for (int i = 0; i < 8; i++) {
                        float kvf = (float)kvh[i];
                        kp[ks * 8 + i] = kvf;
                        ksum[ks * 8 + i] += WE[e] * kvf;
                    }
                }
            }
#pragma unroll
            for (int i = 0; i < 16; i++) y[i] += dt * (1.f / 6.f) * ksum[i];
        }
        if (wv == 0) {   // pred/loss at ti=iv+1
#pragma unroll
            for (int ks = 0; ks < 2; ks++) {
                size_t idx = ((size_t)b * TT + iv + 1) * DD + 32 * ks + 8 * q;
                float4 p0 = make_float4(y[ks * 8 + 0], y[ks * 8 + 1], y[ks * 8 + 2], y[ks * 8 + 3]);
                float4 p1 = make_float4(y[ks * 8 + 4], y[ks * 8 + 5], y[ks * 8 + 6], y[ks * 8 + 7]);
                *(float4*)&pred[idx] = p0;
                *(float4*)&pred[idx + 4] = p1;
                float4 lf0 = *(const float4*)&lfeat[idx], lf1 = *(const float4*)&lfeat[idx + 4];
                float4 lm0 = *(const float4*)&lmask[idx], lm1 = *(const float4*)&lmask[idx + 4];
                float4 lo0, lo1;
                lo0.x = (p0.x - lf0.x) * (p0.x - lf0.x) * (1.f - lm0.x);
                lo0.y = (p0.y - lf0.y) * (p0.y - lf0.y) * (1.f - lm0.y);
                lo0.z = (p0.z - lf0.z) * (p0.z - lf0.z) * (1.f - lm0.z);
                lo0.w = (p0.w - lf0.w) * (p0.w - lf0.w) * (1.f - lm0.w);
                lo1.x = (p1.x - lf1.x) * (p1.x - lf1.x) * (1.f - lm1.x);
                lo1.y = (p1.y - lf1.y) * (p1.y - lf1.y) * (1.f - lm1.y);
                lo1.z = (p1.z - lf1.z) * (p1.z - lf1.z) * (1.f - lm1.z);
                lo1.w = (p1.w - lf1.w) * (p1.w - lf1.w) * (1.f - lm1.w);
                *(float4*)&losso[idx] = lo0;
                *(float4*)&losso[idx + 4] = lo1;
            }
        }
    }
}

extern "C" void kernel_launch(void* const* d_in, const int* in_sizes, int n_in,
                              void* d_out, int out_size, void* d_ws, size_t ws_size,
                              hipStream_t stream)
{
    const float* x      = (const float*)d_in[0];
    const int* lengths  = (const int*)d_in[1];
    const float* lfeat  = (const float*)d_in[2];
    const float* ltime  = (const float*)d_in[3];
    const float* lmask  = (const float*)d_in[4];
    const float* W_ih   = (const float*)d_in[5];
    const float* W_hh   = (const float*)d_in[6];
    const float* b_ih   = (const float*)d_in[7];
    const float* b_hh   = (const float*)d_in[8];
    const float* Wp1    = (const float*)d_in[9];
    const float* bp1    = (const float*)d_in[10];
    const float* Wp2    = (const float*)d_in[11];
    const float* bp2    = (const float*)d_in[12];
    const float* Wd1    = (const float*)d_in[13];
    const float* bd1    = (const float*)d_in[14];
    const float* Wd2    = (const float*)d_in[15];
    const float* bd2    = (const float*)d_in[16];

    float* pred  = (float*)d_out;
    float* losso = pred + (size_t)BB * TT * DD;

    char* ws = (char*)d_ws;
    h4*       xwf    = (h4*)(ws + 0);                  // 268435456
    h4*       BhhV   = (h4*)(ws + 268435456);          //    262144
    h4*       BhhL   = (h4*)(ws + 268697600);          //    131072
    h4*       BhhS   = (h4*)(ws + 268828672);          //    131072
    _Float16* Bih    = (_Float16*)(ws + 268959744);    //    327680
    float*    pooled = (float*)(ws + 269287424);       //    524288
    float*    y0ws   = (float*)(ws + 269811712);       //    131072
    h4*       A1f    = (h4*)(ws + 269942784);          //     32768
    h4*       A2f    = (h4*)(ws + 269975552);          //     32768

    prep_kernel<<<448, 256, 0, stream>>>(W_hh, W_ih, Wd1, Wd2, BhhV, BhhL, BhhS, Bih, A1f, A2f);
    xw_kernel<<<2048, 256, 0, stream>>>(x, Bih, b_ih, b_hh, xwf);
    lstm_kernel<<<32, 512, 0, stream>>>((const h8*)BhhV, (const h8*)BhhL, (const h8*)BhhS,
                                        xwf, lengths, pooled);
    head_kernel<<<BB, 256, 0, stream>>>(pooled, Wp1, bp1, Wp2, bp2, y0ws);
    ode_kernel<<<32, 256, 0, stream>>>(y0ws, (const h8*)A1f, bd1, (const h8*)A2f, bd2,
                                       ltime, lfeat, lmask, pred, losso);
}

// Round 7
// 2560.907 us; speedup vs baseline: 1.0438x; 1.0438x over previous
//
#include <hip/hip_runtime.h>
#include <hip/hip_bf16.h>

#define BB 512
#define SS 256
#define HH 256
#define DD 64
#define TT 50
#define GG 1024   // 4*H
#define INW 129

typedef _Float16 h4 __attribute__((ext_vector_type(4)));
typedef _Float16 h8 __attribute__((ext_vector_type(8)));
typedef __fp16 hf2 __attribute__((ext_vector_type(2)));   // builtin-facing f16 pair
typedef float f32x4 __attribute__((ext_vector_type(4)));
typedef unsigned int u32;

__device__ inline float sigf(float x) { return 1.f / (1.f + __expf(-x)); }
__device__ inline float tanhf_(float x) { return 1.f - 2.f / (__expf(2.f * x) + 1.f); }

__device__ inline u32 pkrtz(float a, float b) {
    hf2 h = __builtin_amdgcn_cvt_pkrtz(a, b);
    return __builtin_bit_cast(u32, h);
}

// ============ prep: unchanged from round 6 (validated) ============
__global__ __launch_bounds__(256) void prep_kernel(
    const float* __restrict__ W_hh, const float* __restrict__ W_ih,
    const float* __restrict__ Wd1, const float* __restrict__ Wd2,
    h4* __restrict__ BhhV4, h4* __restrict__ BhhL4, h4* __restrict__ BhhS4,
    _Float16* __restrict__ Bih, h4* __restrict__ A1f4, h4* __restrict__ A2f4)
{
    int idx = blockIdx.x * 256 + threadIdx.x;
    if (idx < 65536) {
        int eh = idx & 1;
        int l = (idx >> 1) & 63;
        int ks = (idx >> 7) & 7;
        int s = (idx >> 10) & 7;
        int w = (idx >> 13) & 7;
        int g = s & 3, jt = s >> 2;
        int n = g * 256 + w * 32 + jt * 16 + (l & 15);
        int k = 32 * ks + 8 * (l >> 4) + 4 * eh;
        float4 v = *(const float4*)(W_hh + (size_t)n * HH + k);
        h4 o; o[0] = (_Float16)v.x; o[1] = (_Float16)v.y; o[2] = (_Float16)v.z; o[3] = (_Float16)v.w;
        if (ks < 4)      BhhV4[(((w * 8 + s) * 4 + ks) * 64 + l) * 2 + eh] = o;
        else if (ks < 6) BhhL4[(((w * 8 + s) * 2 + (ks - 4)) * 64 + l) * 2 + eh] = o;
        else             BhhS4[(((w * 8 + s) * 2 + (ks - 6)) * 64 + l) * 2 + eh] = o;
    } else if (idx < 106496) {
        int fj = idx - 65536;
        int eh = fj & 1;
        int l = (fj >> 1) & 63;
        int si = fj >> 7;              // [0,320) = ntile*5 + ks
        int ks = si % 5;
        int ntile = si / 5;
        int n = ntile * 16 + (l & 15);
        int k = 32 * ks + 8 * (l >> 4) + 4 * eh;
        h4 o;
#pragma unroll
        for (int i = 0; i < 4; i++) {
            int kk = k + i;
            o[i] = (_Float16)((kk < INW) ? W_ih[(size_t)n * INW + kk] : 0.f);
        }
        *(h4*)(Bih + (size_t)fj * 4) = o;
    } else if (idx < 110592) {
        int fj = idx - 106496;         // A1f: 32 slots * 64 lanes * 2
        int eh = fj & 1;
        int l = (fj >> 1) & 63;
        int slot = fj >> 7;            // t*2+ks
        int ks = slot & 1, t = slot >> 1;
        int row = 16 * t + (l & 15);
        int k = 32 * ks + 8 * (l >> 4) + 4 * eh;
        h4 o;
#pragma unroll
        for (int i = 0; i < 4; i++) o[i] = (_Float16)Wd1[(size_t)row * DD + k + i];
        A1f4[fj] = o;
    } else if (idx < 114688) {
        int fj = idx - 110592;         // A2f: 32 slots * 64 lanes * 2
        int eh = fj & 1;
        int l = (fj >> 1) & 63;
        int slot = fj >> 7;            // t2*8+ks
        int ks = slot & 7, t2 = slot >> 3;
        int row = 16 * t2 + (l & 15);
        int k = 32 * ks + 8 * (l >> 4) + 4 * eh;
        h4 o;
#pragma unroll
        for (int i = 0; i < 4; i++) o[i] = (_Float16)Wd2[(size_t)row * HH + k + i];
        A2f4[fj] = o;
    }
}

// ============ xw GEMM (MFMA): validated, unchanged ============
__global__ __launch_bounds__(256) void xw_kernel(
    const float* __restrict__ x, const _Float16* __restrict__ Bih,
    const float* __restrict__ b_ih, const float* __restrict__ b_hh,
    h4* __restrict__ xwf)
{
    __shared__ __align__(16) _Float16 ash[4][5][64][8];   // 20 KB, A-frag layout
    int tid = threadIdx.x;
    int w4 = tid >> 6, l = tid & 63;
    int bx = blockIdx.x;
    int t = bx >> 3, Bb = bx & 7;           // 64 batch-rows: b = Bb*64 + rr

    for (int i = tid; i < 64 * 160; i += 256) {
        int rr = i / 160, kk = i % 160;
        float v = (kk < INW) ? x[((size_t)(Bb * 64 + rr) * SS + t) * INW + kk] : 0.f;
        ash[rr >> 4][kk >> 5][(((kk & 31) >> 3) << 4) + (rr & 15)][kk & 7] = (_Float16)v;
    }
    __syncthreads();

    h8 A[4][5];
#pragma unroll
    for (int ms = 0; ms < 4; ms++)
#pragma unroll
        for (int ks = 0; ks < 5; ks++)
            A[ms][ks] = *(h8*)&ash[ms][ks][l][0];

    const h8* Bih8 = (const h8*)Bih;
    for (int nt16 = 0; nt16 < 16; nt16++) {
        int ntile = w4 * 16 + nt16;
        h8 Bv[5];
#pragma unroll
        for (int ks = 0; ks < 5; ks++) Bv[ks] = Bih8[(ntile * 5 + ks) * 64 + l];
        int nb = ntile * 16 + (l & 15);
        float bias = b_ih[nb] + b_hh[nb];
        f32x4 acc[4];
#pragma unroll
        for (int ms = 0; ms < 4; ms++) acc[ms] = (f32x4){0.f, 0.f, 0.f, 0.f};
#pragma unroll
        for (int ks = 0; ks < 5; ks++)
#pragma unroll
            for (int ms = 0; ms < 4; ms++)
                acc[ms] = __builtin_amdgcn_mfma_f32_16x16x32_f16(A[ms][ks], Bv[ks], acc[ms], 0, 0, 0);
        int slot = ((ntile & 15) >> 1) * 8 + (ntile & 1) * 4 + (ntile >> 4);
#pragma unroll
        for (int ms = 0; ms < 4; ms++) {
            int bg = Bb * 4 + ms;
            h4 o;
#pragma unroll
            for (int r = 0; r < 4; r++) o[r] = (_Float16)(acc[ms][r] + bias);
            xwf[(((size_t)bg * SS + t) * 64 + slot) * 64 + l] = o;
        }
    }
}

// ============ LSTM: exact round-5 kernel (measured 1108 us; register-feasible config) ============
__global__ __launch_bounds__(512, 2) void lstm_kernel(
    const h8* __restrict__ BhhV, const h8* __restrict__ BhhL, const h8* __restrict__ BhhS,
    const h4* __restrict__ xwf, const int* __restrict__ lengths, float* __restrict__ pooled)
{
    __shared__ __align__(16) _Float16 Wlds[65536];        // 128 KB: ks4-5 weight fragments
    __shared__ __align__(16) _Float16 hbuf[2][8][64][8];  // 16 KB double-buffered A-frag h
    int tid = threadIdx.x;
    int w = tid >> 6, l = tid & 63;
    int bg = blockIdx.x;

    {   // copy ks4-5 weights into LDS (linear, 128 KB)
        const uint4* src = (const uint4*)BhhL;
        uint4* dst = (uint4*)Wlds;
#pragma unroll
        for (int i = 0; i < 16; i++) dst[i * 512 + tid] = src[i * 512 + tid];
    }

    h8 Wv[8][4];
#pragma unroll
    for (int s = 0; s < 8; s++)
#pragma unroll
        for (int ks = 0; ks < 4; ks++)
            Wv[s][ks] = BhhV[((w * 8 + s) * 4 + ks) * 64 + l];

    int len_[4];
    float c_[2][4], pa[2][4];
#pragma unroll
    for (int r = 0; r < 4; r++) {
        int b = 4 * (l >> 4) + r;
        len_[r] = lengths[bg * 16 + b];
#pragma unroll
        for (int jt = 0; jt < 2; jt++) { c_[jt][r] = 0.f; pa[jt][r] = 0.f; }
    }

    {   // zero h buffers (h0 = 0): 1024 uint4, 2 per thread
        uint4* hz = (uint4*)hbuf;
        hz[tid] = make_uint4(0, 0, 0, 0);
        hz[512 + tid] = make_uint4(0, 0, 0, 0);
    }
    __syncthreads();

    int cur = 0;
    for (int t = 0; t < SS; t++) {
        const h4* xpb = xwf + (((size_t)bg * SS + t) * 64 + w * 8) * 64 + l;
        int zoff = 0;
        asm volatile("" : "+v"(zoff));            // block LICM: force per-step re-load of streamed weights
        const h8* bS = BhhS + zoff;
#pragma unroll
        for (int jt = 0; jt < 2; jt++) {
            h4 xv[4];
#pragma unroll
            for (int g = 0; g < 4; g++) xv[g] = xpb[(jt * 4 + g) * 64];
            h8 Ws[4];
#pragma unroll
            for (int g = 0; g < 4; g++) Ws[g] = bS[((w * 8 + jt * 4 + g) * 2 + 0) * 64 + l];
            f32x4 acc[4];
#pragma unroll
            for (int g = 0; g < 4; g++) acc[g] = (f32x4){0.f, 0.f, 0.f, 0.f};
            // ks 0-3 from VGPR/AGPR weights
#pragma unroll
            for (int ks = 0; ks < 4; ks++) {
                h8 A = *(const h8*)&hbuf[cur][ks][l][0];
#pragma unroll
                for (int g = 0; g < 4; g++)
                    acc[g] = __builtin_amdgcn_mfma_f32_16x16x32_f16(A, Wv[jt * 4 + g][ks], acc[g], 0, 0, 0);
            }
            // ks 6 (streamed, landed)
            {
                h8 A = *(const h8*)&hbuf[cur][6][l][0];
#pragma unroll
                for (int g = 0; g < 4; g++)
                    acc[g] = __builtin_amdgcn_mfma_f32_16x16x32_f16(A, Ws[g], acc[g], 0, 0, 0);
            }
            // reissue stream for ks 7 into same regs
#pragma unroll
            for (int g = 0; g < 4; g++) Ws[g] = bS[((w * 8 + jt * 4 + g) * 2 + 1) * 64 + l];
            // ks 4-5 from LDS
#pragma unroll
            for (int ks = 4; ks < 6; ks++) {
                h8 A = *(const h8*)&hbuf[cur][ks][l][0];
#pragma unroll
                for (int g = 0; g < 4; g++) {
                    h8 Bw = *(const h8*)&Wlds[(((w * 8 + jt * 4 + g) * 2 + (ks - 4)) * 64 + l) * 8];
                    acc[g] = __builtin_amdgcn_mfma_f32_16x16x32_f16(A, Bw, acc[g], 0, 0, 0);
                }
            }
            // ks 7
            {
                h8 A = *(const h8*)&hbuf[cur][7][l][0];
#pragma unroll
                for (int g = 0; g < 4; g++)
                    acc[g] = __builtin_amdgcn_mfma_f32_16x16x32_f16(A, Ws[g], acc[g], 0, 0, 0);
            }
            // gates + h update
#pragma unroll
            for (int r = 0; r < 4; r++) {
                float gi = acc[0][r] + (float)xv[0][r];
                float gf = acc[1][r] + (float)xv[1][r];
                float gg = acc[2][r] + (float)xv[2][r];
                float go = acc[3][r] + (float)xv[3][r];
                float cc = sigf(gf) * c_[jt][r] + sigf(gi) * tanhf_(gg);
                c_[jt][r] = cc;
                float hh = sigf(go) * tanhf_(cc);
                if (t < len_[r]) pa[jt][r] += hh;
                int b = 4 * (l >> 4) + r;
                int j = w * 32 + jt * 16 + (l & 15);
                hbuf[cur ^ 1][j >> 5][(((j & 31) >> 3) << 4) + b][j & 7] = (_Float16)hh;
            }
        }
        __syncthreads();
        cur ^= 1;
    }

#pragma unroll
    for (int jt = 0; jt < 2; jt++)
#pragma unroll
        for (int r = 0; r < 4; r++) {
            int b = 4 * (l >> 4) + r;
            int j = w * 32 + jt * 16 + (l & 15);
            pooled[(size_t)(bg * 16 + b) * HH + j] = pa[jt][r] / (float)len_[r];
        }
}

// ============ head: unchanged ============
__global__ __launch_bounds__(256) void head_kernel(
    const float* __restrict__ pooled, const float* __restrict__ Wp1,
    const float* __restrict__ bp1, const float* __restrict__ Wp2,
    const float* __restrict__ bp2, float* __restrict__ y0ws)
{
    __shared__ __align__(16) float psh[HH];
    __shared__ __align__(16) float rsh[HH];
    int tid = threadIdx.x, b = blockIdx.x;
    psh[tid] = pooled[(size_t)b * HH + tid];
    __syncthreads();
    float a = bp1[tid];
    const float* wr = Wp1 + (size_t)tid * HH;
#pragma unroll 8
    for (int k = 0; k < HH; k += 4) {
        float4 w = *(const float4*)(wr + k);
        a += psh[k] * w.x + psh[k + 1] * w.y + psh[k + 2] * w.z + psh[k + 3] * w.w;
    }
    rsh[tid] = fmaxf(a, 0.f);
    __syncthreads();
    if (tid < DD) {
        float acc = bp2[tid];
        const float* w2 = Wp2 + (size_t)tid * HH;
#pragma unroll 8
        for (int h = 0; h < HH; h += 4) {
            float4 w = *(const float4*)(w2 + h);
            acc += rsh[h] * w.x + rsh[h + 1] * w.y + rsh[h + 2] * w.z + rsh[h + 3] * w.w;
        }
        y0ws[(size_t)b * DD + tid] = acc;
    }
}

// ============ ODE v4: same MFMA structure, 512 blocks x 1 batch (2 blocks/CU overlap) ============
// All 16 lane-columns redundantly compute the SAME batch (b = blockIdx.x); stores gated to bb==0.
// Rationale: the per-eval chain (2 barriers + 2 LDS RTs) is the floor; co-residency of 2 blocks/CU
// lets one block's waves fill the pipes while the other stalls at a barrier.
__global__ __launch_bounds__(256) void ode_kernel(
    const float* __restrict__ y0ws, const h8* __restrict__ A1f,
    const float* __restrict__ bd1, const h8* __restrict__ A2f,
    const float* __restrict__ bd2, const float* __restrict__ ltime,
    const float* __restrict__ lfeat, const float* __restrict__ lmask,
    float* __restrict__ pred, float* __restrict__ losso)
{
    __shared__ __align__(16) _Float16 hX[4096];   // swizzled [bb][i], 8 KB
    __shared__ __align__(16) _Float16 kX[1024];   // swizzled [bb][j], 2 KB
    int tid = threadIdx.x;
    int wv = tid >> 6, l = tid & 63;
    int q = l >> 4, bb = l & 15;
    int b = blockIdx.x;                           // ONE batch per block

    // weights as A-fragments, resident in regs
    h8 A1[4][2];
#pragma unroll
    for (int tt = 0; tt < 4; tt++)
#pragma unroll
        for (int ks = 0; ks < 2; ks++)
            A1[tt][ks] = A1f[((4 * wv + tt) * 2 + ks) * 64 + l];
    h8 A2[8];
#pragma unroll
    for (int ks = 0; ks < 8; ks++) A2[ks] = A2f[(wv * 8 + ks) * 64 + l];

    float bd1c[4][4];
#pragma unroll
    for (int tt = 0; tt < 4; tt++)
#pragma unroll
        for (int r = 0; r < 4; r++) bd1c[tt][r] = bd1[16 * (4 * wv + tt) + 4 * q + r];
    float bd2c[4];
#pragma unroll
    for (int r = 0; r < 4; r++) bd2c[r] = bd2[16 * wv + 4 * q + r];

    float y[16], kp[16], ksum[16];
#pragma unroll
    for (int ks = 0; ks < 2; ks++)
#pragma unroll
        for (int e = 0; e < 8; e++) {
            y[ks * 8 + e] = y0ws[(size_t)b * DD + 32 * ks + 8 * q + e];
            kp[ks * 8 + e] = 0.f;
        }

    if (wv == 0 && bb == 0) {   // pred/loss at ti=0 (lanes q=0..3 cover all 64 dims)
#pragma unroll
        for (int ks = 0; ks < 2; ks++) {
            size_t idx = ((size_t)b * TT + 0) * DD + 32 * ks + 8 * q;
            float4 p0 = make_float4(y[ks * 8 + 0], y[ks * 8 + 1], y[ks * 8 + 2], y[ks * 8 + 3]);
            float4 p1 = make_float4(y[ks * 8 + 4], y[ks * 8 + 5], y[ks * 8 + 6], y[ks * 8 + 7]);
            *(float4*)&pred[idx] = p0;
            *(float4*)&pred[idx + 4] = p1;
            float4 lf0 = *(const float4*)&lfeat[idx], lf1 = *(const float4*)&lfeat[idx + 4];
            float4 lm0 = *(const float4*)&lmask[idx], lm1 = *(const float4*)&lmask[idx + 4];
            float4 lo0, lo1;
            lo0.x = (p0.x - lf0.x) * (p0.x - lf0.x) * (1.f - lm0.x);
            lo0.y = (p0.y - lf0.y) * (p0.y - lf0.y) * (1.f - lm0.y);
            lo0.z = (p0.z - lf0.z) * (p0.z - lf0.z) * (1.f - lm0.z);
            lo0.w = (p0.w - lf0.w) * (p0.w - lf0.w) * (1.f - lm0.w);
            lo1.x = (p1.x - lf1.x) * (p1.x - lf1.x) * (1.f - lm1.x);
            lo1.y = (p1.y - lf1.y) * (p1.y - lf1.y) * (1.f - lm1.y);
            lo1.z = (p1.z - lf1.z) * (p1.z - lf1.z) * (1.f - lm1.z);
            lo1.w = (p1.w - lf1.w) * (p1.w - lf1.w) * (1.f - lm1.w);
            *(float4*)&losso[idx] = lo0;
            *(float4*)&losso[idx + 4] = lo1;
        }
    }

    for (int iv = 0; iv < TT - 1; iv++) {
        float t0 = ltime[(size_t)b * TT + iv], t1 = ltime[(size_t)b * TT + iv + 1];
        float dt = (t1 - t0) * 0.125f;
        for (int ss = 0; ss < 8; ss++) {
#pragma unroll
            for (int i = 0; i < 16; i++) ksum[i] = 0.f;
            const float AE[4] = {0.f, 0.5f, 0.5f, 1.f};
            const float WE[4] = {1.f, 2.f, 2.f, 1.f};
#pragma unroll
            for (int e = 0; e < 4; e++) {
                // build B1 (y-stage, f16 B-frag)
                h8 B1[2];
#pragma unroll
                for (int ks = 0; ks < 2; ks++) {
                    float ye[8];
#pragma unroll
                    for (int i = 0; i < 8; i++) ye[i] = y[ks * 8 + i] + AE[e] * dt * kp[ks * 8 + i];
                    uint4 u;
                    u.x = pkrtz(ye[0], ye[1]); u.y = pkrtz(ye[2], ye[3]);
                    u.z = pkrtz(ye[4], ye[5]); u.w = pkrtz(ye[6], ye[7]);
                    B1[ks] = __builtin_bit_cast(h8, u);
                }
                // GEMV1: 4 tiles x 2 ks
                f32x4 C1[4];
#pragma unroll
                for (int tt = 0; tt < 4; tt++) C1[tt] = (f32x4){0.f, 0.f, 0.f, 0.f};
#pragma unroll
                for (int ks = 0; ks < 2; ks++)
#pragma unroll
                    for (int tt = 0; tt < 4; tt++)
                        C1[tt] = __builtin_amdgcn_mfma_f32_16x16x32_f16(A1[tt][ks], B1[ks], C1[tt], 0, 0, 0);
                // relu + bias, pack, write hX
#pragma unroll
                for (int tt = 0; tt < 4; tt++) {
                    float h0 = fmaxf(C1[tt][0] + bd1c[tt][0], 0.f);
                    float h1 = fmaxf(C1[tt][1] + bd1c[tt][1], 0.f);
                    float h2 = fmaxf(C1[tt][2] + bd1c[tt][2], 0.f);
                    float h3 = fmaxf(C1[tt][3] + bd1c[tt][3], 0.f);
                    int i0 = 16 * (4 * wv + tt) + 4 * q;
                    int idx = (bb * 256 + i0) ^ ((bb & 7) << 3);
                    *(uint2*)&hX[idx] = make_uint2(pkrtz(h0, h1), pkrtz(h2, h3));
                }
                __syncthreads();
                // GEMV2: 1 tile x 8 ks, 2 chains
                f32x4 Ca = (f32x4){0.f, 0.f, 0.f, 0.f}, Cb = (f32x4){0.f, 0.f, 0.f, 0.f};
#pragma unroll
                for (int ks = 0; ks < 8; ks += 2) {
                    h8 B2a = *(const h8*)&hX[(bb * 256 + 32 * ks + 8 * q) ^ ((bb & 7) << 3)];
                    h8 B2b = *(const h8*)&hX[(bb * 256 + 32 * (ks + 1) + 8 * q) ^ ((bb & 7) << 3)];
                    Ca = __builtin_amdgcn_mfma_f32_16x16x32_f16(A2[ks], B2a, Ca, 0, 0, 0);
                    Cb = __builtin_amdgcn_mfma_f32_16x16x32_f16(A2[ks + 1], B2b, Cb, 0, 0, 0);
                }
                {
                    float k0 = Ca[0] + Cb[0] + bd2c[0];
                    float k1 = Ca[1] + Cb[1] + bd2c[1];
                    float k2 = Ca[2] + Cb[2] + bd2c[2];
                    float k3 = Ca[3] + Cb[3] + bd2c[3];
                    int j0 = 16 * wv + 4 * q;
                    int idx = (bb * 64 + j0) ^ ((bb & 7) << 3);
                    *(uint2*)&kX[idx] = make_uint2(pkrtz(k0, k1), pkrtz(k2, k3));
                }
                __syncthreads();
                // read kv back in B1 layout; update kp/ksum
#pragma unroll
                for (int ks = 0; ks < 2; ks++) {
                    h8 kvh = *(const h8*)&kX[(bb * 64 + 32 * ks + 8 * q) ^ ((bb & 7) << 3)];
#pragma unroll
                    for (int i = 0; i < 8; i++) {
                        float kvf = (float)kvh[i];
                        kp[ks * 8 + i] = kvf;
                        ksum[ks * 8 + i] += WE[e] * kvf;
                    }
                }
            }
#pragma unroll
            for (int i = 0; i < 16; i++) y[i] += dt * (1.f / 6.f) * ksum[i];
        }
        if (wv == 0 && bb == 0) {   // pred/loss at ti=iv+1
#pragma unroll
            for (int ks = 0; ks < 2; ks++) {
                size_t idx = ((size_t)b * TT + iv + 1) * DD + 32 * ks + 8 * q;
                float4 p0 = make_float4(y[ks * 8 + 0], y[ks * 8 + 1], y[ks * 8 + 2], y[ks * 8 + 3]);
                float4 p1 = make_float4(y[ks * 8 + 4], y[ks * 8 + 5], y[ks * 8 + 6], y[ks * 8 + 7]);
                *(float4*)&pred[idx] = p0;
                *(float4*)&pred[idx + 4] = p1;
                float4 lf0 = *(const float4*)&lfeat[idx], lf1 = *(const float4*)&lfeat[idx + 4];
                float4 lm0 = *(const float4*)&lmask[idx], lm1 = *(const float4*)&lmask[idx + 4];
                float4 lo0, lo1;
                lo0.x = (p0.x - lf0.x) * (p0.x - lf0.x) * (1.f - lm0.x);
                lo0.y = (p0.y - lf0.y) * (p0.y - lf0.y) * (1.f - lm0.y);
                lo0.z = (p0.z - lf0.z) * (p0.z - lf0.z) * (1.f - lm0.z);
                lo0.w = (p0.w - lf0.w) * (p0.w - lf0.w) * (1.f - lm0.w);
                lo1.x = (p1.x - lf1.x) * (p1.x - lf1.x) * (1.f - lm1.x);
                lo1.y = (p1.y - lf1.y) * (p1.y - lf1.y) * (1.f - lm1.y);
                lo1.z = (p1.z - lf1.z) * (p1.z - lf1.z) * (1.f - lm1.z);
                lo1.w = (p1.w - lf1.w) * (p1.w - lf1.w) * (1.f - lm1.w);
                *(float4*)&losso[idx] = lo0;
                *(float4*)&losso[idx + 4] = lo1;
            }
        }
    }
}

extern "C" void kernel_launch(void* const* d_in, const int* in_sizes, int n_in,
                              void* d_out, int out_size, void* d_ws, size_t ws_size,
                              hipStream_t stream)
{
    const float* x      = (const float*)d_in[0];
    const int* lengths  = (const int*)d_in[1];
    const float* lfeat  = (const float*)d_in[2];
    const float* ltime  = (const float*)d_in[3];
    const float* lmask  = (const float*)d_in[4];
    const float* W_ih   = (const float*)d_in[5];
    const float* W_hh   = (const float*)d_in[6];
    const float* b_ih   = (const float*)d_in[7];
    const float* b_hh   = (const float*)d_in[8];
    const float* Wp1    = (const float*)d_in[9];
    const float* bp1    = (const float*)d_in[10];
    const float* Wp2    = (const float*)d_in[11];
    const float* bp2    = (const float*)d_in[12];
    const float* Wd1    = (const float*)d_in[13];
    const float* bd1    = (const float*)d_in[14];
    const float* Wd2    = (const float*)d_in[15];
    const float* bd2    = (const float*)d_in[16];

    float* pred  = (float*)d_out;
    float* losso = pred + (size_t)BB * TT * DD;

    char* ws = (char*)d_ws;
    h4*       xwf    = (h4*)(ws + 0);                  // 268435456
    h4*       BhhV   = (h4*)(ws + 268435456);          //    262144
    h4*       BhhL   = (h4*)(ws + 268697600);          //    131072
    h4*       BhhS   = (h4*)(ws + 268828672);          //    131072
    _Float16* Bih    = (_Float16*)(ws + 268959744);    //    327680
    float*    pooled = (float*)(ws + 269287424);       //    524288
    float*    y0ws   = (float*)(ws + 269811712);       //    131072
    h4*       A1f    = (h4*)(ws + 269942784);          //     32768
    h4*       A2f    = (h4*)(ws + 269975552);          //     32768

    prep_kernel<<<448, 256, 0, stream>>>(W_hh, W_ih, Wd1, Wd2, BhhV, BhhL, BhhS, Bih, A1f, A2f);
    xw_kernel<<<2048, 256, 0, stream>>>(x, Bih, b_ih, b_hh, xwf);
    lstm_kernel<<<32, 512, 0, stream>>>((const h8*)BhhV, (const h8*)BhhL, (const h8*)BhhS,
                                        xwf, lengths, pooled);
    head_kernel<<<BB, 256, 0, stream>>>(pooled, Wp1, bp1, Wp2, bp2, y0ws);
    ode_kernel<<<512, 256, 0, stream>>>(y0ws, (const h8*)A1f, bd1, (const h8*)A2f, bd2,
                                        ltime, lfeat, lmask, pred, losso);
}